// Round 1
// baseline (1568.930 us; speedup 1.0000x reference)
//
#include <hip/hip_runtime.h>
#include <math.h>

#define NCH 128
#define NGRAPH 128

// ---------------- CSR build ----------------

__global__ void k_deg(const int* __restrict__ dst, int* __restrict__ deg, int E) {
    int e = blockIdx.x * 256 + threadIdx.x;
    if (e < E) atomicAdd(&deg[dst[e]], 1);
}

// single-block exclusive scan over n elements (n ~ 100K, trivial cost)
__global__ void k_scan(const int* __restrict__ deg, int* __restrict__ rowptr, int n) {
    __shared__ int tmp[1024];
    __shared__ int carry;
    int tid = threadIdx.x;
    if (tid == 0) carry = 0;
    __syncthreads();
    for (int base = 0; base < n; base += 1024) {
        int cbase = carry;
        int i = base + tid;
        int v = (i < n) ? deg[i] : 0;
        tmp[tid] = v;
        __syncthreads();
        for (int off = 1; off < 1024; off <<= 1) {
            int t = (tid >= off) ? tmp[tid - off] : 0;
            __syncthreads();
            tmp[tid] += t;
            __syncthreads();
        }
        if (i < n) rowptr[i] = cbase + tmp[tid] - v;
        __syncthreads();
        if (tid == 0) carry = cbase + tmp[1023];
        __syncthreads();
    }
    if (tid == 0) rowptr[n] = carry;
}

__global__ void k_fill(const int* __restrict__ src, const int* __restrict__ dst,
                       const int* __restrict__ rowptr, int* __restrict__ cursor,
                       int* __restrict__ col, int E) {
    int e = blockIdx.x * 256 + threadIdx.x;
    if (e < E) {
        int d = dst[e];
        int p = rowptr[d] + atomicAdd(&cursor[d], 1);
        col[p] = src[e];
    }
}

// ---------------- aggregation: out[n] = in[n] + sum_{s in N(n)} in[s] ----------------
// 8 nodes per 256-thread block, 32 lanes per node, float4 per lane.

__global__ void k_agg(const float* __restrict__ in, const int* __restrict__ rowptr,
                      const int* __restrict__ col, float* __restrict__ out, int N) {
    int n = blockIdx.x * 8 + (threadIdx.x >> 5);
    int lane = threadIdx.x & 31;
    if (n >= N) return;
    const float4* in4 = (const float4*)in;
    float4 acc = in4[(long)n * 32 + lane];
    int beg = rowptr[n], end = rowptr[n + 1];
    for (int j = beg; j < end; ++j) {
        int s = col[j];
        float4 v = in4[(long)s * 32 + lane];
        acc.x += v.x; acc.y += v.y; acc.z += v.z; acc.w += v.w;
    }
    ((float4*)out)[(long)n * 32 + lane] = acc;
}

// ---------------- GEMM [N x 128] @ [128 x 128] + BN + ReLU ----------------
// block: 256 threads, tile 32 rows x 128 cols, per-thread 4x4. A in LDS (stride 132,
// conflict-free), W streamed from L1/L2.

__launch_bounds__(256)
__global__ void k_gemm(const float* __restrict__ A, const float* __restrict__ W,
                       const float* __restrict__ bias, const float* __restrict__ gamma,
                       const float* __restrict__ beta, const float* __restrict__ mean,
                       const float* __restrict__ var, float* __restrict__ out, int N) {
    __shared__ float As[32 * 132];
    int tid = threadIdx.x;
    int row0 = blockIdx.x * 32;

    #pragma unroll
    for (int rep = 0; rep < 4; ++rep) {
        int idx = rep * 1024 + tid * 4;
        int r = idx >> 7, c = idx & 127;
        float4 v = make_float4(0.f, 0.f, 0.f, 0.f);
        if (row0 + r < N) v = *(const float4*)(A + (long)(row0 + r) * NCH + c);
        *(float4*)&As[r * 132 + c] = v;
    }
    __syncthreads();

    int tx = tid & 31, ty = tid >> 5;
    float acc[4][4] = {};
    #pragma unroll 8
    for (int k = 0; k < 128; ++k) {
        float4 w = *(const float4*)(W + k * NCH + tx * 4);
        float a0 = As[(ty * 4 + 0) * 132 + k];
        float a1 = As[(ty * 4 + 1) * 132 + k];
        float a2 = As[(ty * 4 + 2) * 132 + k];
        float a3 = As[(ty * 4 + 3) * 132 + k];
        acc[0][0] += a0 * w.x; acc[0][1] += a0 * w.y; acc[0][2] += a0 * w.z; acc[0][3] += a0 * w.w;
        acc[1][0] += a1 * w.x; acc[1][1] += a1 * w.y; acc[1][2] += a1 * w.z; acc[1][3] += a1 * w.w;
        acc[2][0] += a2 * w.x; acc[2][1] += a2 * w.y; acc[2][2] += a2 * w.z; acc[2][3] += a2 * w.w;
        acc[3][0] += a3 * w.x; acc[3][1] += a3 * w.y; acc[3][2] += a3 * w.z; acc[3][3] += a3 * w.w;
    }

    int c0 = tx * 4;
    float scale[4], shift[4];
    #pragma unroll
    for (int j = 0; j < 4; ++j) {
        int c = c0 + j;
        float s = gamma[c] * rsqrtf(var[c] + 1e-5f);
        scale[j] = s;
        shift[j] = (bias[c] - mean[c]) * s + beta[c];
    }
    #pragma unroll
    for (int i = 0; i < 4; ++i) {
        int r = row0 + ty * 4 + i;
        if (r < N) {
            float4 o;
            o.x = fmaxf(acc[i][0] * scale[0] + shift[0], 0.f);
            o.y = fmaxf(acc[i][1] * scale[1] + shift[1], 0.f);
            o.z = fmaxf(acc[i][2] * scale[2] + shift[2], 0.f);
            o.w = fmaxf(acc[i][3] * scale[3] + shift[3], 0.f);
            *(float4*)(out + (long)r * NCH + c0) = o;
        }
    }
}

// ---------------- global_add_pool (batch sorted -> run-length + rare atomics) ----------------

__global__ void k_pool(const float* __restrict__ h, const int* __restrict__ batch,
                       float* __restrict__ pooled, int sec, int N) {
    int start = blockIdx.x * 128;
    int c = threadIdx.x & 127;
    int rh = threadIdx.x >> 7;  // 0 or 1
    float acc = 0.f;
    int gcur = -1;
    for (int r = start + rh; r < start + 128; r += 2) {
        if (r >= N) break;
        int g = batch[r];
        if (g != gcur) {
            if (gcur >= 0) atomicAdd(&pooled[gcur * 512 + sec * 128 + c], acc);
            gcur = g;
            acc = 0.f;
        }
        acc += h[(long)r * NCH + c];
    }
    if (gcur >= 0) atomicAdd(&pooled[gcur * 512 + sec * 128 + c], acc);
}

// ---------------- MLP head + log_softmax: one block per graph ----------------

__launch_bounds__(256)
__global__ void k_mlp(const float* __restrict__ pooled,
                      const float* __restrict__ w1, const float* __restrict__ b1,
                      const float* __restrict__ w2, const float* __restrict__ b2,
                      float* __restrict__ out) {
    __shared__ float row[512];
    __shared__ float hid[256];
    __shared__ float o10[10];
    int g = blockIdx.x, tid = threadIdx.x;
    row[tid] = pooled[g * 512 + tid];
    row[tid + 256] = pooled[g * 512 + 256 + tid];
    __syncthreads();
    float acc = b1[tid];
    for (int k = 0; k < 512; ++k) acc += row[k] * w1[k * 256 + tid];
    hid[tid] = fmaxf(acc, 0.f);
    __syncthreads();
    if (tid < 10) {
        float o = b2[tid];
        for (int k = 0; k < 256; ++k) o += hid[k] * w2[k * 10 + tid];
        o10[tid] = o;
        out[g * 10 + tid] = o;
    }
    __syncthreads();
    if (tid == 0) {
        float m = o10[0];
        for (int j = 1; j < 10; ++j) m = fmaxf(m, o10[j]);
        float s = 0.f;
        for (int j = 0; j < 10; ++j) s += expf(o10[j] - m);
        float ls = m + logf(s);
        for (int j = 0; j < 10; ++j) out[NGRAPH * 10 + g * 10 + j] = o10[j] - ls;
    }
}

// ---------------- launch ----------------

extern "C" void kernel_launch(void* const* d_in, const int* in_sizes, int n_in,
                              void* d_out, int out_size, void* d_ws, size_t ws_size,
                              hipStream_t stream) {
    const float* x     = (const float*)d_in[0];
    const int*   eix   = (const int*)d_in[1];
    const int*   eiy   = (const int*)d_in[2];
    const int*   batch = (const int*)d_in[3];
    const float* convW = (const float*)d_in[4];
    const float* convB = (const float*)d_in[5];
    const float* gma   = (const float*)d_in[6];
    const float* bta   = (const float*)d_in[7];
    const float* mea   = (const float*)d_in[8];
    const float* var   = (const float*)d_in[9];
    const float* w1    = (const float*)d_in[10];
    const float* b1    = (const float*)d_in[11];
    const float* w2    = (const float*)d_in[12];
    const float* b2    = (const float*)d_in[13];
    float* out = (float*)d_out;

    int N = in_sizes[0] / NCH;
    int E = in_sizes[1] / 2;

    char* p = (char*)d_ws;
    auto alloc = [&](size_t bytes) {
        char* r = p;
        p += (bytes + 255) & ~(size_t)255;
        return r;
    };
    int* rowx     = (int*)alloc((size_t)(N + 1) * 4);
    int* rowy     = (int*)alloc((size_t)(N + 1) * 4);
    int* colx     = (int*)alloc((size_t)E * 4);
    int* coly     = (int*)alloc((size_t)E * 4);
    int* tmp      = (int*)alloc((size_t)N * 4);
    float* aggb   = (float*)alloc((size_t)N * NCH * 4);
    float* bufA   = (float*)alloc((size_t)N * NCH * 4);
    float* bufB   = (float*)alloc((size_t)N * NCH * 4);
    float* pooled = (float*)alloc((size_t)NGRAPH * 512 * 4);

    const int* srcx = eix;
    const int* dstx = eix + E;
    const int* srcy = eiy;
    const int* dsty = eiy + E;

    int EB = (E + 255) / 256;
    int NB8 = (N + 7) / 8;
    int GB = (N + 31) / 32;
    int PB = (N + 127) / 128;

    // ---- CSR x ----
    hipMemsetAsync(tmp, 0, (size_t)N * 4, stream);
    k_deg<<<EB, 256, 0, stream>>>(dstx, tmp, E);
    k_scan<<<1, 1024, 0, stream>>>(tmp, rowx, N);
    hipMemsetAsync(tmp, 0, (size_t)N * 4, stream);
    k_fill<<<EB, 256, 0, stream>>>(srcx, dstx, rowx, tmp, colx, E);
    // ---- CSR y ----
    hipMemsetAsync(tmp, 0, (size_t)N * 4, stream);
    k_deg<<<EB, 256, 0, stream>>>(dsty, tmp, E);
    k_scan<<<1, 1024, 0, stream>>>(tmp, rowy, N);
    hipMemsetAsync(tmp, 0, (size_t)N * 4, stream);
    k_fill<<<EB, 256, 0, stream>>>(srcy, dsty, rowy, tmp, coly, E);

    hipMemsetAsync(pooled, 0, (size_t)NGRAPH * 512 * 4, stream);

    // conv1_x: x -> bufA
    k_agg<<<NB8, 256, 0, stream>>>(x, rowx, colx, aggb, N);
    k_gemm<<<GB, 256, 0, stream>>>(aggb, convW + 0 * NCH * NCH, convB + 0 * NCH,
                                   gma + 0 * NCH, bta + 0 * NCH, mea + 0 * NCH, var + 0 * NCH,
                                   bufA, N);
    k_pool<<<PB, 256, 0, stream>>>(bufA, batch, pooled, 0, N);

    // conv2_x: bufA -> bufB
    k_agg<<<NB8, 256, 0, stream>>>(bufA, rowx, colx, aggb, N);
    k_gemm<<<GB, 256, 0, stream>>>(aggb, convW + 1 * NCH * NCH, convB + 1 * NCH,
                                   gma + 1 * NCH, bta + 1 * NCH, mea + 1 * NCH, var + 1 * NCH,
                                   bufB, N);
    k_pool<<<PB, 256, 0, stream>>>(bufB, batch, pooled, 1, N);

    // conv1_y: x -> bufA (h1x no longer needed)
    k_agg<<<NB8, 256, 0, stream>>>(x, rowy, coly, aggb, N);
    k_gemm<<<GB, 256, 0, stream>>>(aggb, convW + 2 * NCH * NCH, convB + 2 * NCH,
                                   gma + 2 * NCH, bta + 2 * NCH, mea + 2 * NCH, var + 2 * NCH,
                                   bufA, N);
    k_pool<<<PB, 256, 0, stream>>>(bufA, batch, pooled, 2, N);

    // conv2_y: bufA -> bufB
    k_agg<<<NB8, 256, 0, stream>>>(bufA, rowy, coly, aggb, N);
    k_gemm<<<GB, 256, 0, stream>>>(aggb, convW + 3 * NCH * NCH, convB + 3 * NCH,
                                   gma + 3 * NCH, bta + 3 * NCH, mea + 3 * NCH, var + 3 * NCH,
                                   bufB, N);
    k_pool<<<PB, 256, 0, stream>>>(bufB, batch, pooled, 3, N);

    // head
    k_mlp<<<NGRAPH, 256, 0, stream>>>(pooled, w1, b1, w2, b2, out);
}

// Round 2
// 1205.912 us; speedup vs baseline: 1.3010x; 1.3010x over previous
//
#include <hip/hip_runtime.h>
#include <math.h>

#define NCH 128
#define NGRAPH 128

// ---------------- CSR build ----------------

__global__ void k_deg(const int* __restrict__ dst, int* __restrict__ deg, int E) {
    int e = blockIdx.x * 256 + threadIdx.x;
    if (e < E) atomicAdd(&deg[dst[e]], 1);
}

// Phase A: per-block (1024 elems) sums
__global__ void k_bsum(const int* __restrict__ deg, int* __restrict__ bsum, int n) {
    int tid = threadIdx.x;
    int i0 = blockIdx.x * 1024 + tid * 4;
    int s = 0;
    if (i0 + 3 < n) {
        int4 v = *(const int4*)(deg + i0);
        s = v.x + v.y + v.z + v.w;
    } else {
        for (int j = 0; j < 4; ++j) if (i0 + j < n) s += deg[i0 + j];
    }
    #pragma unroll
    for (int off = 32; off; off >>= 1) s += __shfl_down(s, off);
    __shared__ int ws[4];
    if ((tid & 63) == 0) ws[tid >> 6] = s;
    __syncthreads();
    if (tid == 0) bsum[blockIdx.x] = ws[0] + ws[1] + ws[2] + ws[3];
}

// Phase B: one wave scans block sums (exclusive, in place), writes total
__global__ void k_scan_sums(int* __restrict__ bsum, int nb, int* __restrict__ total_out) {
    int lane = threadIdx.x;
    int carry = 0;
    for (int base = 0; base < nb; base += 64) {
        int v = (base + lane < nb) ? bsum[base + lane] : 0;
        int incl = v;
        #pragma unroll
        for (int off = 1; off < 64; off <<= 1) {
            int t = __shfl_up(incl, off);
            if (lane >= off) incl += t;
        }
        if (base + lane < nb) bsum[base + lane] = carry + incl - v;
        carry += __shfl(incl, 63);
    }
    if (lane == 0) *total_out = carry;
}

// Phase C: per-block exclusive scan + block offset -> rowptr
__global__ void k_scan_blk(const int* __restrict__ deg, const int* __restrict__ boff,
                           int* __restrict__ rowptr, int n) {
    int tid = threadIdx.x;
    int lane = tid & 63, wave = tid >> 6;
    int i0 = blockIdx.x * 1024 + tid * 4;
    int v0 = 0, v1 = 0, v2 = 0, v3 = 0;
    if (i0 + 3 < n) {
        int4 v = *(const int4*)(deg + i0);
        v0 = v.x; v1 = v.y; v2 = v.z; v3 = v.w;
    } else {
        if (i0 + 0 < n) v0 = deg[i0 + 0];
        if (i0 + 1 < n) v1 = deg[i0 + 1];
        if (i0 + 2 < n) v2 = deg[i0 + 2];
        if (i0 + 3 < n) v3 = deg[i0 + 3];
    }
    int tot = v0 + v1 + v2 + v3;
    int incl = tot;
    #pragma unroll
    for (int off = 1; off < 64; off <<= 1) {
        int t = __shfl_up(incl, off);
        if (lane >= off) incl += t;
    }
    __shared__ int wsum[4];
    if (lane == 63) wsum[wave] = incl;
    __syncthreads();
    int wbase = 0;
    for (int w = 0; w < wave; ++w) wbase += wsum[w];
    int base = boff[blockIdx.x] + wbase + (incl - tot);
    if (i0 + 3 < n) {
        int4 r;
        r.x = base;
        r.y = base + v0;
        r.z = base + v0 + v1;
        r.w = base + v0 + v1 + v2;
        *(int4*)(rowptr + i0) = r;
    } else {
        if (i0 + 0 < n) rowptr[i0 + 0] = base;
        if (i0 + 1 < n) rowptr[i0 + 1] = base + v0;
        if (i0 + 2 < n) rowptr[i0 + 2] = base + v0 + v1;
        if (i0 + 3 < n) rowptr[i0 + 3] = base + v0 + v1 + v2;
    }
}

__global__ void k_fill(const int* __restrict__ src, const int* __restrict__ dst,
                       const int* __restrict__ rowptr, int* __restrict__ cursor,
                       int* __restrict__ col, int E) {
    int e = blockIdx.x * 256 + threadIdx.x;
    if (e < E) {
        int d = dst[e];
        int p = rowptr[d] + atomicAdd(&cursor[d], 1);
        col[p] = src[e];
    }
}

// ---------------- aggregation: out[n] = in[n] + sum_{s in N(n)} in[s] ----------------

__global__ void k_agg(const float* __restrict__ in, const int* __restrict__ rowptr,
                      const int* __restrict__ col, float* __restrict__ out, int N) {
    int n = blockIdx.x * 8 + (threadIdx.x >> 5);
    int lane = threadIdx.x & 31;
    if (n >= N) return;
    const float4* in4 = (const float4*)in;
    float4 acc = in4[(long)n * 32 + lane];
    int beg = rowptr[n], end = rowptr[n + 1];
    for (int j = beg; j < end; ++j) {
        int s = col[j];
        float4 v = in4[(long)s * 32 + lane];
        acc.x += v.x; acc.y += v.y; acc.z += v.z; acc.w += v.w;
    }
    ((float4*)out)[(long)n * 32 + lane] = acc;
}

// ---------------- GEMM [N x 128] @ [128 x 128] + BN + ReLU ----------------

__launch_bounds__(256)
__global__ void k_gemm(const float* __restrict__ A, const float* __restrict__ W,
                       const float* __restrict__ bias, const float* __restrict__ gamma,
                       const float* __restrict__ beta, const float* __restrict__ mean,
                       const float* __restrict__ var, float* __restrict__ out, int N) {
    __shared__ float As[32 * 132];
    int tid = threadIdx.x;
    int row0 = blockIdx.x * 32;

    #pragma unroll
    for (int rep = 0; rep < 4; ++rep) {
        int idx = rep * 1024 + tid * 4;
        int r = idx >> 7, c = idx & 127;
        float4 v = make_float4(0.f, 0.f, 0.f, 0.f);
        if (row0 + r < N) v = *(const float4*)(A + (long)(row0 + r) * NCH + c);
        *(float4*)&As[r * 132 + c] = v;
    }
    __syncthreads();

    int tx = tid & 31, ty = tid >> 5;
    float acc[4][4] = {};
    #pragma unroll 8
    for (int k = 0; k < 128; ++k) {
        float4 w = *(const float4*)(W + k * NCH + tx * 4);
        float a0 = As[(ty * 4 + 0) * 132 + k];
        float a1 = As[(ty * 4 + 1) * 132 + k];
        float a2 = As[(ty * 4 + 2) * 132 + k];
        float a3 = As[(ty * 4 + 3) * 132 + k];
        acc[0][0] += a0 * w.x; acc[0][1] += a0 * w.y; acc[0][2] += a0 * w.z; acc[0][3] += a0 * w.w;
        acc[1][0] += a1 * w.x; acc[1][1] += a1 * w.y; acc[1][2] += a1 * w.z; acc[1][3] += a1 * w.w;
        acc[2][0] += a2 * w.x; acc[2][1] += a2 * w.y; acc[2][2] += a2 * w.z; acc[2][3] += a2 * w.w;
        acc[3][0] += a3 * w.x; acc[3][1] += a3 * w.y; acc[3][2] += a3 * w.z; acc[3][3] += a3 * w.w;
    }

    int c0 = tx * 4;
    float scale[4], shift[4];
    #pragma unroll
    for (int j = 0; j < 4; ++j) {
        int c = c0 + j;
        float s = gamma[c] * rsqrtf(var[c] + 1e-5f);
        scale[j] = s;
        shift[j] = (bias[c] - mean[c]) * s + beta[c];
    }
    #pragma unroll
    for (int i = 0; i < 4; ++i) {
        int r = row0 + ty * 4 + i;
        if (r < N) {
            float4 o;
            o.x = fmaxf(acc[i][0] * scale[0] + shift[0], 0.f);
            o.y = fmaxf(acc[i][1] * scale[1] + shift[1], 0.f);
            o.z = fmaxf(acc[i][2] * scale[2] + shift[2], 0.f);
            o.w = fmaxf(acc[i][3] * scale[3] + shift[3], 0.f);
            *(float4*)(out + (long)r * NCH + c0) = o;
        }
    }
}

// ---------------- global_add_pool ----------------

__global__ void k_pool(const float* __restrict__ h, const int* __restrict__ batch,
                       float* __restrict__ pooled, int sec, int N) {
    int start = blockIdx.x * 128;
    int c = threadIdx.x & 127;
    int rh = threadIdx.x >> 7;  // 0 or 1
    float acc = 0.f;
    int gcur = -1;
    for (int r = start + rh; r < start + 128; r += 2) {
        if (r >= N) break;
        int g = batch[r];
        if (g != gcur) {
            if (gcur >= 0) atomicAdd(&pooled[gcur * 512 + sec * 128 + c], acc);
            gcur = g;
            acc = 0.f;
        }
        acc += h[(long)r * NCH + c];
    }
    if (gcur >= 0) atomicAdd(&pooled[gcur * 512 + sec * 128 + c], acc);
}

// ---------------- MLP head + log_softmax ----------------

__launch_bounds__(256)
__global__ void k_mlp(const float* __restrict__ pooled,
                      const float* __restrict__ w1, const float* __restrict__ b1,
                      const float* __restrict__ w2, const float* __restrict__ b2,
                      float* __restrict__ out) {
    __shared__ float row[512];
    __shared__ float hid[256];
    __shared__ float o10[10];
    int g = blockIdx.x, tid = threadIdx.x;
    row[tid] = pooled[g * 512 + tid];
    row[tid + 256] = pooled[g * 512 + 256 + tid];
    __syncthreads();
    float acc = b1[tid];
    for (int k = 0; k < 512; ++k) acc += row[k] * w1[k * 256 + tid];
    hid[tid] = fmaxf(acc, 0.f);
    __syncthreads();
    if (tid < 10) {
        float o = b2[tid];
        for (int k = 0; k < 256; ++k) o += hid[k] * w2[k * 10 + tid];
        o10[tid] = o;
        out[g * 10 + tid] = o;
    }
    __syncthreads();
    if (tid == 0) {
        float m = o10[0];
        for (int j = 1; j < 10; ++j) m = fmaxf(m, o10[j]);
        float s = 0.f;
        for (int j = 0; j < 10; ++j) s += expf(o10[j] - m);
        float ls = m + logf(s);
        for (int j = 0; j < 10; ++j) out[NGRAPH * 10 + g * 10 + j] = o10[j] - ls;
    }
}

// ---------------- launch ----------------

extern "C" void kernel_launch(void* const* d_in, const int* in_sizes, int n_in,
                              void* d_out, int out_size, void* d_ws, size_t ws_size,
                              hipStream_t stream) {
    const float* x     = (const float*)d_in[0];
    const int*   eix   = (const int*)d_in[1];
    const int*   eiy   = (const int*)d_in[2];
    const int*   batch = (const int*)d_in[3];
    const float* convW = (const float*)d_in[4];
    const float* convB = (const float*)d_in[5];
    const float* gma   = (const float*)d_in[6];
    const float* bta   = (const float*)d_in[7];
    const float* mea   = (const float*)d_in[8];
    const float* var   = (const float*)d_in[9];
    const float* w1    = (const float*)d_in[10];
    const float* b1    = (const float*)d_in[11];
    const float* w2    = (const float*)d_in[12];
    const float* b2    = (const float*)d_in[13];
    float* out = (float*)d_out;

    int N = in_sizes[0] / NCH;
    int E = in_sizes[1] / 2;

    char* p = (char*)d_ws;
    auto alloc = [&](size_t bytes) {
        char* r = p;
        p += (bytes + 255) & ~(size_t)255;
        return r;
    };
    int* rowx     = (int*)alloc((size_t)(N + 1) * 4);
    int* rowy     = (int*)alloc((size_t)(N + 1) * 4);
    int* colx     = (int*)alloc((size_t)E * 4);
    int* coly     = (int*)alloc((size_t)E * 4);
    int* tmp      = (int*)alloc((size_t)N * 4);
    int* bsum     = (int*)alloc(4096);
    float* aggb   = (float*)alloc((size_t)N * NCH * 4);
    float* bufA   = (float*)alloc((size_t)N * NCH * 4);
    float* bufB   = (float*)alloc((size_t)N * NCH * 4);
    float* pooled = (float*)alloc((size_t)NGRAPH * 512 * 4);

    const int* srcx = eix;
    const int* dstx = eix + E;
    const int* srcy = eiy;
    const int* dsty = eiy + E;

    int EB = (E + 255) / 256;
    int NB8 = (N + 7) / 8;
    int GB = (N + 31) / 32;
    int PB = (N + 127) / 128;
    int NBS = (N + 1023) / 1024;   // scan blocks

    // ---- CSR x ----
    hipMemsetAsync(tmp, 0, (size_t)N * 4, stream);
    k_deg<<<EB, 256, 0, stream>>>(dstx, tmp, E);
    k_bsum<<<NBS, 256, 0, stream>>>(tmp, bsum, N);
    k_scan_sums<<<1, 64, 0, stream>>>(bsum, NBS, rowx + N);
    k_scan_blk<<<NBS, 256, 0, stream>>>(tmp, bsum, rowx, N);
    hipMemsetAsync(tmp, 0, (size_t)N * 4, stream);
    k_fill<<<EB, 256, 0, stream>>>(srcx, dstx, rowx, tmp, colx, E);
    // ---- CSR y ----
    hipMemsetAsync(tmp, 0, (size_t)N * 4, stream);
    k_deg<<<EB, 256, 0, stream>>>(dsty, tmp, E);
    k_bsum<<<NBS, 256, 0, stream>>>(tmp, bsum, N);
    k_scan_sums<<<1, 64, 0, stream>>>(bsum, NBS, rowy + N);
    k_scan_blk<<<NBS, 256, 0, stream>>>(tmp, bsum, rowy, N);
    hipMemsetAsync(tmp, 0, (size_t)N * 4, stream);
    k_fill<<<EB, 256, 0, stream>>>(srcy, dsty, rowy, tmp, coly, E);

    hipMemsetAsync(pooled, 0, (size_t)NGRAPH * 512 * 4, stream);

    // conv1_x: x -> bufA
    k_agg<<<NB8, 256, 0, stream>>>(x, rowx, colx, aggb, N);
    k_gemm<<<GB, 256, 0, stream>>>(aggb, convW + 0 * NCH * NCH, convB + 0 * NCH,
                                   gma + 0 * NCH, bta + 0 * NCH, mea + 0 * NCH, var + 0 * NCH,
                                   bufA, N);
    k_pool<<<PB, 256, 0, stream>>>(bufA, batch, pooled, 0, N);

    // conv2_x: bufA -> bufB
    k_agg<<<NB8, 256, 0, stream>>>(bufA, rowx, colx, aggb, N);
    k_gemm<<<GB, 256, 0, stream>>>(aggb, convW + 1 * NCH * NCH, convB + 1 * NCH,
                                   gma + 1 * NCH, bta + 1 * NCH, mea + 1 * NCH, var + 1 * NCH,
                                   bufB, N);
    k_pool<<<PB, 256, 0, stream>>>(bufB, batch, pooled, 1, N);

    // conv1_y: x -> bufA
    k_agg<<<NB8, 256, 0, stream>>>(x, rowy, coly, aggb, N);
    k_gemm<<<GB, 256, 0, stream>>>(aggb, convW + 2 * NCH * NCH, convB + 2 * NCH,
                                   gma + 2 * NCH, bta + 2 * NCH, mea + 2 * NCH, var + 2 * NCH,
                                   bufA, N);
    k_pool<<<PB, 256, 0, stream>>>(bufA, batch, pooled, 2, N);

    // conv2_y: bufA -> bufB
    k_agg<<<NB8, 256, 0, stream>>>(bufA, rowy, coly, aggb, N);
    k_gemm<<<GB, 256, 0, stream>>>(aggb, convW + 3 * NCH * NCH, convB + 3 * NCH,
                                   gma + 3 * NCH, bta + 3 * NCH, mea + 3 * NCH, var + 3 * NCH,
                                   bufB, N);
    k_pool<<<PB, 256, 0, stream>>>(bufB, batch, pooled, 3, N);

    // head
    k_mlp<<<NGRAPH, 256, 0, stream>>>(pooled, w1, b1, w2, b2, out);
}

// Round 3
// 789.103 us; speedup vs baseline: 1.9882x; 1.5282x over previous
//
#include <hip/hip_runtime.h>
#include <math.h>

#define NCH 128
#define NGRAPH 128

typedef __attribute__((ext_vector_type(8))) short short8v;
typedef __attribute__((ext_vector_type(4))) float f32x4;

static __device__ __forceinline__ float bf_lo(unsigned u) { return __uint_as_float(u << 16); }
static __device__ __forceinline__ float bf_hi(unsigned u) { return __uint_as_float(u & 0xffff0000u); }
static __device__ __forceinline__ unsigned short f2bf(float f) {
    unsigned u = __float_as_uint(f);
    return (unsigned short)((u + 0x7fffu + ((u >> 16) & 1u)) >> 16);
}

// ---------------- dtype prep ----------------

// x f32 -> bf16, 4 elems/thread, grid-stride
__global__ void k_cvt(const float* __restrict__ in, unsigned short* __restrict__ outb, long n4) {
    long i = (long)blockIdx.x * 256 + threadIdx.x;
    long stride = (long)gridDim.x * 256;
    for (; i < n4; i += stride) {
        float4 v = *(const float4*)(in + i * 4);
        ushort4 o;
        o.x = f2bf(v.x); o.y = f2bf(v.y); o.z = f2bf(v.z); o.w = f2bf(v.w);
        *(ushort4*)(outb + i * 4) = o;
    }
}

// convW[i][k][n] f32 -> Wt[i][n][k] bf16 (transposed)
__global__ void k_prepw(const float* __restrict__ W, unsigned short* __restrict__ Wt) {
    int idx = blockIdx.x * 256 + threadIdx.x;   // 65536 total
    int i = idx >> 14, rem = idx & 16383;
    int n = rem >> 7, k = rem & 127;
    Wt[idx] = f2bf(W[i * 16384 + k * 128 + n]);
}

// ---------------- CSR build ----------------

__global__ void k_deg(const int* __restrict__ dst, int* __restrict__ deg, int E) {
    int e = blockIdx.x * 256 + threadIdx.x;
    if (e < E) atomicAdd(&deg[dst[e]], 1);
}

__global__ void k_bsum(const int* __restrict__ deg, int* __restrict__ bsum, int n) {
    int tid = threadIdx.x;
    int i0 = blockIdx.x * 1024 + tid * 4;
    int s = 0;
    if (i0 + 3 < n) {
        int4 v = *(const int4*)(deg + i0);
        s = v.x + v.y + v.z + v.w;
    } else {
        for (int j = 0; j < 4; ++j) if (i0 + j < n) s += deg[i0 + j];
    }
    #pragma unroll
    for (int off = 32; off; off >>= 1) s += __shfl_down(s, off);
    __shared__ int ws[4];
    if ((tid & 63) == 0) ws[tid >> 6] = s;
    __syncthreads();
    if (tid == 0) bsum[blockIdx.x] = ws[0] + ws[1] + ws[2] + ws[3];
}

__global__ void k_scan_sums(int* __restrict__ bsum, int nb, int* __restrict__ total_out) {
    int lane = threadIdx.x;
    int carry = 0;
    for (int base = 0; base < nb; base += 64) {
        int v = (base + lane < nb) ? bsum[base + lane] : 0;
        int incl = v;
        #pragma unroll
        for (int off = 1; off < 64; off <<= 1) {
            int t = __shfl_up(incl, off);
            if (lane >= off) incl += t;
        }
        if (base + lane < nb) bsum[base + lane] = carry + incl - v;
        carry += __shfl(incl, 63);
    }
    if (lane == 0) *total_out = carry;
}

__global__ void k_scan_blk(const int* __restrict__ deg, const int* __restrict__ boff,
                           int* __restrict__ rowptr, int n) {
    int tid = threadIdx.x;
    int lane = tid & 63, wave = tid >> 6;
    int i0 = blockIdx.x * 1024 + tid * 4;
    int v0 = 0, v1 = 0, v2 = 0, v3 = 0;
    if (i0 + 3 < n) {
        int4 v = *(const int4*)(deg + i0);
        v0 = v.x; v1 = v.y; v2 = v.z; v3 = v.w;
    } else {
        if (i0 + 0 < n) v0 = deg[i0 + 0];
        if (i0 + 1 < n) v1 = deg[i0 + 1];
        if (i0 + 2 < n) v2 = deg[i0 + 2];
        if (i0 + 3 < n) v3 = deg[i0 + 3];
    }
    int tot = v0 + v1 + v2 + v3;
    int incl = tot;
    #pragma unroll
    for (int off = 1; off < 64; off <<= 1) {
        int t = __shfl_up(incl, off);
        if (lane >= off) incl += t;
    }
    __shared__ int wsum[4];
    if (lane == 63) wsum[wave] = incl;
    __syncthreads();
    int wbase = 0;
    for (int w = 0; w < wave; ++w) wbase += wsum[w];
    int base = boff[blockIdx.x] + wbase + (incl - tot);
    if (i0 + 3 < n) {
        int4 r;
        r.x = base;
        r.y = base + v0;
        r.z = base + v0 + v1;
        r.w = base + v0 + v1 + v2;
        *(int4*)(rowptr + i0) = r;
    } else {
        if (i0 + 0 < n) rowptr[i0 + 0] = base;
        if (i0 + 1 < n) rowptr[i0 + 1] = base + v0;
        if (i0 + 2 < n) rowptr[i0 + 2] = base + v0 + v1;
        if (i0 + 3 < n) rowptr[i0 + 3] = base + v0 + v1 + v2;
    }
}

__global__ void k_fill(const int* __restrict__ src, const int* __restrict__ dst,
                       const int* __restrict__ rowptr, int* __restrict__ cursor,
                       int* __restrict__ col, int E) {
    int e = blockIdx.x * 256 + threadIdx.x;
    if (e < E) {
        int d = dst[e];
        int p = rowptr[d] + atomicAdd(&cursor[d], 1);
        col[p] = src[e];
    }
}

// ---------------- aggregation (bf16): out[n] = in[n] + sum_{s in N(n)} in[s] ----------------
// 16 nodes per 256-thread block, 16 lanes per node, uint4 (8 bf16) per lane.

__global__ void k_agg(const unsigned short* __restrict__ inb, const int* __restrict__ rowptr,
                      const int* __restrict__ col, unsigned short* __restrict__ outb, int N) {
    int n = blockIdx.x * 16 + (threadIdx.x >> 4);
    int l = threadIdx.x & 15;
    if (n >= N) return;
    const uint4* in16 = (const uint4*)inb;
    float acc[8] = {};
    {
        uint4 v = in16[(long)n * 16 + l];
        acc[0] += bf_lo(v.x); acc[1] += bf_hi(v.x);
        acc[2] += bf_lo(v.y); acc[3] += bf_hi(v.y);
        acc[4] += bf_lo(v.z); acc[5] += bf_hi(v.z);
        acc[6] += bf_lo(v.w); acc[7] += bf_hi(v.w);
    }
    int beg = rowptr[n], end = rowptr[n + 1];
    for (int j = beg; j < end; ++j) {
        int s = col[j];
        uint4 v = in16[(long)s * 16 + l];
        acc[0] += bf_lo(v.x); acc[1] += bf_hi(v.x);
        acc[2] += bf_lo(v.y); acc[3] += bf_hi(v.y);
        acc[4] += bf_lo(v.z); acc[5] += bf_hi(v.z);
        acc[6] += bf_lo(v.w); acc[7] += bf_hi(v.w);
    }
    uint4 o;
    o.x = (unsigned)f2bf(acc[0]) | ((unsigned)f2bf(acc[1]) << 16);
    o.y = (unsigned)f2bf(acc[2]) | ((unsigned)f2bf(acc[3]) << 16);
    o.z = (unsigned)f2bf(acc[4]) | ((unsigned)f2bf(acc[5]) << 16);
    o.w = (unsigned)f2bf(acc[6]) | ((unsigned)f2bf(acc[7]) << 16);
    ((uint4*)outb)[(long)n * 16 + l] = o;
}

// ---------------- MFMA GEMM [N x 128] @ [128 x 128] + BN + ReLU, bf16 in/out ----------------
// block 256 = 4 waves; tile 64 rows; wave handles 16 rows x 128 cols (8 col-tiles).
// Wt (bf16 [n][k]) staged to LDS with XOR swizzle (addr ^= (n&7)<<4) -> conflict-free b128 reads.

__launch_bounds__(256)
__global__ void k_gemm(const unsigned short* __restrict__ Ab, const unsigned short* __restrict__ Wt,
                       const float* __restrict__ bias, const float* __restrict__ gamma,
                       const float* __restrict__ beta, const float* __restrict__ mean,
                       const float* __restrict__ var, unsigned short* __restrict__ outb, int N) {
    __shared__ unsigned short WL[128 * 128];
    int tid = threadIdx.x;
    // stage Wt -> LDS (swizzled)
    #pragma unroll
    for (int i = 0; i < 8; ++i) {
        int idx16 = i * 256 + tid;            // 16-byte chunk id, 2048 total
        int n = idx16 >> 4, k8 = idx16 & 15;
        unsigned ba = (unsigned)((n * 256 + k8 * 16) ^ ((n & 7) << 4));
        uint4 v = *(const uint4*)(Wt + n * 128 + k8 * 8);
        *(uint4*)((char*)WL + ba) = v;
    }
    __syncthreads();

    int wave = tid >> 6, lane = tid & 63;
    int lr = lane & 15, lg = lane >> 4;       // lg in 0..3
    int row0 = blockIdx.x * 64 + wave * 16;

    f32x4 acc[8] = {};
    #pragma unroll
    for (int k0 = 0; k0 < 128; k0 += 32) {
        short8v a = *(const short8v*)(Ab + (long)(row0 + lr) * NCH + k0 + lg * 8);
        #pragma unroll
        for (int c = 0; c < 8; ++c) {
            int n = c * 16 + lr;
            unsigned ba = (unsigned)((n * 256 + k0 * 2 + lg * 16) ^ ((lr & 7) << 4));
            short8v b = *(const short8v*)((char*)WL + ba);
            acc[c] = __builtin_amdgcn_mfma_f32_16x16x32_bf16(a, b, acc[c], 0, 0, 0);
        }
    }

    // epilogue: lane holds D[row0 + lg*4 + r][c*16 + lr], r=0..3
    #pragma unroll
    for (int c = 0; c < 8; ++c) {
        int colc = c * 16 + lr;
        float s = gamma[colc] * rsqrtf(var[colc] + 1e-5f);
        float sh = (bias[colc] - mean[colc]) * s + beta[colc];
        #pragma unroll
        for (int r = 0; r < 4; ++r) {
            int row = row0 + lg * 4 + r;
            if (row < N) {
                float v = fmaxf(acc[c][r] * s + sh, 0.f);
                outb[(long)row * NCH + colc] = f2bf(v);
            }
        }
    }
}

// ---------------- global_add_pool (bf16 h, f32 pooled) ----------------

__global__ void k_pool(const unsigned short* __restrict__ h, const int* __restrict__ batch,
                       float* __restrict__ pooled, int sec, int N) {
    int start = blockIdx.x * 128;
    int c2 = threadIdx.x & 63;     // u32 col pair
    int rh = threadIdx.x >> 6;     // 0..3
    const unsigned* h32 = (const unsigned*)h;
    float a0 = 0.f, a1 = 0.f;
    int gcur = -1;
    for (int r = start + rh; r < start + 128; r += 4) {
        if (r >= N) break;
        int g = batch[r];
        if (g != gcur) {
            if (gcur >= 0) {
                atomicAdd(&pooled[gcur * 512 + sec * 128 + c2 * 2 + 0], a0);
                atomicAdd(&pooled[gcur * 512 + sec * 128 + c2 * 2 + 1], a1);
            }
            gcur = g;
            a0 = a1 = 0.f;
        }
        unsigned u = h32[(long)r * 64 + c2];
        a0 += bf_lo(u);
        a1 += bf_hi(u);
    }
    if (gcur >= 0) {
        atomicAdd(&pooled[gcur * 512 + sec * 128 + c2 * 2 + 0], a0);
        atomicAdd(&pooled[gcur * 512 + sec * 128 + c2 * 2 + 1], a1);
    }
}

// ---------------- MLP head + log_softmax ----------------

__launch_bounds__(256)
__global__ void k_mlp(const float* __restrict__ pooled,
                      const float* __restrict__ w1, const float* __restrict__ b1,
                      const float* __restrict__ w2, const float* __restrict__ b2,
                      float* __restrict__ out) {
    __shared__ float row[512];
    __shared__ float hid[256];
    __shared__ float o10[10];
    int g = blockIdx.x, tid = threadIdx.x;
    row[tid] = pooled[g * 512 + tid];
    row[tid + 256] = pooled[g * 512 + 256 + tid];
    __syncthreads();
    float acc = b1[tid];
    for (int k = 0; k < 512; ++k) acc += row[k] * w1[k * 256 + tid];
    hid[tid] = fmaxf(acc, 0.f);
    __syncthreads();
    if (tid < 10) {
        float o = b2[tid];
        for (int k = 0; k < 256; ++k) o += hid[k] * w2[k * 10 + tid];
        o10[tid] = o;
        out[g * 10 + tid] = o;
    }
    __syncthreads();
    if (tid == 0) {
        float m = o10[0];
        for (int j = 1; j < 10; ++j) m = fmaxf(m, o10[j]);
        float s = 0.f;
        for (int j = 0; j < 10; ++j) s += expf(o10[j] - m);
        float ls = m + logf(s);
        for (int j = 0; j < 10; ++j) out[NGRAPH * 10 + g * 10 + j] = o10[j] - ls;
    }
}

// ---------------- launch ----------------

extern "C" void kernel_launch(void* const* d_in, const int* in_sizes, int n_in,
                              void* d_out, int out_size, void* d_ws, size_t ws_size,
                              hipStream_t stream) {
    const float* x     = (const float*)d_in[0];
    const int*   eix   = (const int*)d_in[1];
    const int*   eiy   = (const int*)d_in[2];
    const int*   batch = (const int*)d_in[3];
    const float* convW = (const float*)d_in[4];
    const float* convB = (const float*)d_in[5];
    const float* gma   = (const float*)d_in[6];
    const float* bta   = (const float*)d_in[7];
    const float* mea   = (const float*)d_in[8];
    const float* var   = (const float*)d_in[9];
    const float* w1    = (const float*)d_in[10];
    const float* b1    = (const float*)d_in[11];
    const float* w2    = (const float*)d_in[12];
    const float* b2    = (const float*)d_in[13];
    float* out = (float*)d_out;

    int N = in_sizes[0] / NCH;
    int E = in_sizes[1] / 2;
    int Npad = N + 64;   // pad rows so GEMM A-loads past N stay in-bounds

    char* p = (char*)d_ws;
    auto alloc = [&](size_t bytes) {
        char* r = p;
        p += (bytes + 255) & ~(size_t)255;
        return r;
    };
    int* rowx     = (int*)alloc((size_t)(N + 1) * 4);
    int* rowy     = (int*)alloc((size_t)(N + 1) * 4);
    int* colx     = (int*)alloc((size_t)E * 4);
    int* coly     = (int*)alloc((size_t)E * 4);
    int* tmp      = (int*)alloc((size_t)N * 4);
    int* bsum     = (int*)alloc(4096);
    unsigned short* xb   = (unsigned short*)alloc((size_t)N * NCH * 2);
    unsigned short* Wt   = (unsigned short*)alloc((size_t)4 * NCH * NCH * 2);
    unsigned short* aggb = (unsigned short*)alloc((size_t)Npad * NCH * 2);
    unsigned short* bufA = (unsigned short*)alloc((size_t)Npad * NCH * 2);
    unsigned short* bufB = (unsigned short*)alloc((size_t)Npad * NCH * 2);
    float* pooled = (float*)alloc((size_t)NGRAPH * 512 * 4);

    const int* srcx = eix;
    const int* dstx = eix + E;
    const int* srcy = eiy;
    const int* dsty = eiy + E;

    int EB = (E + 255) / 256;
    int AB = (N + 15) / 16;          // agg blocks
    int GB = (N + 63) / 64;          // gemm blocks
    int PB = (N + 127) / 128;        // pool blocks
    int NBS = (N + 1023) / 1024;     // scan blocks

    // dtype prep
    k_cvt<<<2048, 256, 0, stream>>>(x, xb, (long)N * 32);
    k_prepw<<<256, 256, 0, stream>>>(convW, Wt);

    // ---- CSR x ----
    hipMemsetAsync(tmp, 0, (size_t)N * 4, stream);
    k_deg<<<EB, 256, 0, stream>>>(dstx, tmp, E);
    k_bsum<<<NBS, 256, 0, stream>>>(tmp, bsum, N);
    k_scan_sums<<<1, 64, 0, stream>>>(bsum, NBS, rowx + N);
    k_scan_blk<<<NBS, 256, 0, stream>>>(tmp, bsum, rowx, N);
    hipMemsetAsync(tmp, 0, (size_t)N * 4, stream);
    k_fill<<<EB, 256, 0, stream>>>(srcx, dstx, rowx, tmp, colx, E);
    // ---- CSR y ----
    hipMemsetAsync(tmp, 0, (size_t)N * 4, stream);
    k_deg<<<EB, 256, 0, stream>>>(dsty, tmp, E);
    k_bsum<<<NBS, 256, 0, stream>>>(tmp, bsum, N);
    k_scan_sums<<<1, 64, 0, stream>>>(bsum, NBS, rowy + N);
    k_scan_blk<<<NBS, 256, 0, stream>>>(tmp, bsum, rowy, N);
    hipMemsetAsync(tmp, 0, (size_t)N * 4, stream);
    k_fill<<<EB, 256, 0, stream>>>(srcy, dsty, rowy, tmp, coly, E);

    hipMemsetAsync(pooled, 0, (size_t)NGRAPH * 512 * 4, stream);

    // conv1_x: xb -> bufA
    k_agg<<<AB, 256, 0, stream>>>(xb, rowx, colx, aggb, N);
    k_gemm<<<GB, 256, 0, stream>>>(aggb, Wt + 0 * NCH * NCH, convB + 0 * NCH,
                                   gma + 0 * NCH, bta + 0 * NCH, mea + 0 * NCH, var + 0 * NCH,
                                   bufA, N);
    k_pool<<<PB, 256, 0, stream>>>(bufA, batch, pooled, 0, N);

    // conv2_x: bufA -> bufB
    k_agg<<<AB, 256, 0, stream>>>(bufA, rowx, colx, aggb, N);
    k_gemm<<<GB, 256, 0, stream>>>(aggb, Wt + 1 * NCH * NCH, convB + 1 * NCH,
                                   gma + 1 * NCH, bta + 1 * NCH, mea + 1 * NCH, var + 1 * NCH,
                                   bufB, N);
    k_pool<<<PB, 256, 0, stream>>>(bufB, batch, pooled, 1, N);

    // conv1_y: xb -> bufA
    k_agg<<<AB, 256, 0, stream>>>(xb, rowy, coly, aggb, N);
    k_gemm<<<GB, 256, 0, stream>>>(aggb, Wt + 2 * NCH * NCH, convB + 2 * NCH,
                                   gma + 2 * NCH, bta + 2 * NCH, mea + 2 * NCH, var + 2 * NCH,
                                   bufA, N);
    k_pool<<<PB, 256, 0, stream>>>(bufA, batch, pooled, 2, N);

    // conv2_y: bufA -> bufB
    k_agg<<<AB, 256, 0, stream>>>(bufA, rowy, coly, aggb, N);
    k_gemm<<<GB, 256, 0, stream>>>(aggb, Wt + 3 * NCH * NCH, convB + 3 * NCH,
                                   gma + 3 * NCH, bta + 3 * NCH, mea + 3 * NCH, var + 3 * NCH,
                                   bufB, N);
    k_pool<<<PB, 256, 0, stream>>>(bufB, batch, pooled, 3, N);

    // head
    k_mlp<<<NGRAPH, 256, 0, stream>>>(pooled, w1, b1, w2, b2, out);
}